// Round 6
// baseline (817.092 us; speedup 1.0000x reference)
//
#include <hip/hip_runtime.h>
#include <hip/hip_bf16.h>
#include <hip/hip_fp16.h>

#define NN   100000
#define EE   1600000
#define ETOT (EE + NN)
#define GG   256
#define BNEPS 1e-5f
#define NBK  391          // buckets of 256 nodes: (NN+255)/256

// ---------------- CSR build: bucketed partition (single-writer cache lines) --

__global__ __launch_bounds__(256) void bucket_count_kernel(
    const int* __restrict__ ei, int* __restrict__ bucket_cnt)
{
    __shared__ int cnt[NBK];
    for (int i = threadIdx.x; i < NBK; i += 256) cnt[i] = 0;
    __syncthreads();
    int base = blockIdx.x * 8192;
    for (int k = threadIdx.x; k < 8192; k += 256) {
        int e = base + k;
        if (e < ETOT) {
            int dst = (e < EE) ? ei[EE + e] : (e - EE);
            atomicAdd(&cnt[dst >> 8], 1);
        }
    }
    __syncthreads();
    for (int i = threadIdx.x; i < NBK; i += 256)
        if (cnt[i]) atomicAdd(&bucket_cnt[i], cnt[i]);
}

__global__ __launch_bounds__(512) void bucket_scan_kernel(
    const int* __restrict__ bucket_cnt, int* __restrict__ bucket_base,
    int* __restrict__ gcursor)
{
    __shared__ int s[512];
    int t = threadIdx.x;
    int v = (t < NBK) ? bucket_cnt[t] : 0;
    s[t] = v;
    __syncthreads();
    int x = v;
    for (int o = 1; o < 512; o <<= 1) {
        int y = (t >= o) ? s[t - o] : 0;
        __syncthreads();
        x += y;
        s[t] = x;
        __syncthreads();
    }
    if (t < NBK) { bucket_base[t] = x - v; gcursor[t] = x - v; }
    if (t == 0) bucket_base[NBK] = ETOT;
}

__global__ __launch_bounds__(256) void partition_kernel(
    const int* __restrict__ ei, int* __restrict__ gcursor, int* __restrict__ part)
{
    __shared__ int cnt[NBK];
    __shared__ int basel[NBK];
    for (int i = threadIdx.x; i < NBK; i += 256) cnt[i] = 0;
    __syncthreads();
    int base = blockIdx.x * 4096;
    for (int k = threadIdx.x; k < 4096; k += 256) {
        int e = base + k;
        if (e < ETOT) {
            int dst = (e < EE) ? ei[EE + e] : (e - EE);
            atomicAdd(&cnt[dst >> 8], 1);
        }
    }
    __syncthreads();
    for (int i = threadIdx.x; i < NBK; i += 256) {
        int c = cnt[i];
        basel[i] = c ? atomicAdd(&gcursor[i], c) : 0;
        cnt[i] = 0;   // reuse as intra-block cursor
    }
    __syncthreads();
    for (int k = threadIdx.x; k < 4096; k += 256) {
        int e = base + k;
        if (e < ETOT) {
            int src, dst;
            if (e < EE) { src = ei[e]; dst = ei[EE + e]; }
            else        { src = e - EE; dst = e - EE; }
            int b = dst >> 8;
            int slot = atomicAdd(&cnt[b], 1);
            part[basel[b] + slot] = src | ((dst & 255) << 17);
        }
    }
}

__global__ __launch_bounds__(256) void csr_build_kernel(
    const int* __restrict__ part, const int* __restrict__ bucket_base,
    int* __restrict__ row_ptr, int* __restrict__ csr_src)
{
    __shared__ int deg[256];
    __shared__ int sc[256];
    int b = blockIdx.x;
    int t = threadIdx.x;
    int beg = bucket_base[b], end = bucket_base[b + 1];
    deg[t] = 0;
    __syncthreads();
    for (int j = beg + t; j < end; j += 256)
        atomicAdd(&deg[(part[j] >> 17) & 255], 1);
    __syncthreads();
    int v = deg[t];
    sc[t] = v;
    __syncthreads();
    int x = v;
    for (int o = 1; o < 256; o <<= 1) {
        int y = (t >= o) ? sc[t - o] : 0;
        __syncthreads();
        x += y;
        sc[t] = x;
        __syncthreads();
    }
    int excl = x - v;
    int node = b * 256 + t;
    if (node < NN) row_ptr[node] = beg + excl;
    __syncthreads();
    deg[t] = beg + excl;   // per-node global cursor
    __syncthreads();
    for (int j = beg + t; j < end; j += 256) {
        int pv = part[j];
        int pos = atomicAdd(&deg[(pv >> 17) & 255], 1);
        csr_src[pos] = pv & 0x1FFFF;
    }
    if (b == 0 && t == 0) row_ptr[NN] = ETOT;
}

// ---------------- layer-1 feature transform (K=5, cheap); h stored fp16 ------

__global__ __launch_bounds__(256) void feat1_kernel(
    const float* __restrict__ xin, const float* __restrict__ W,
    const float* __restrict__ pw, const float* __restrict__ pb,
    const float* __restrict__ a_src, const float* __restrict__ a_dst,
    __half* __restrict__ h16, float* __restrict__ esrc, float* __restrict__ edst,
    float* __restrict__ rout, int nN)
{
    constexpr int F_IN = 5, F_OUT = 64;
    int t = threadIdx.x;
    int n = blockIdx.x * 4 + t / F_OUT;
    int f = t % F_OUT;
    if (n >= nN) return;
    float acc = 0.f, racc = 0.f;
#pragma unroll
    for (int k = 0; k < F_IN; ++k) {
        float xv = xin[n * F_IN + k];
        acc  += xv * W[k * F_OUT + f];
        racc += xv * pw[k * F_OUT + f];
    }
    h16[(size_t)n * F_OUT + f] = __float2half_rn(acc);
    rout[(size_t)n * F_OUT + f] = racc + pb[f];
    float es = acc * a_src[f];
    float ed = acc * a_dst[f];
#pragma unroll
    for (int off = 16; off > 0; off >>= 1) {
        es += __shfl_xor(es, off, 32);
        ed += __shfl_xor(ed, off, 32);
    }
    if ((t & 31) == 0) {
        int head = (f >> 5) & 1;
        esrc[n * 2 + head] = es;
        edst[n * 2 + head] = ed;
    }
}

// ---------------- register-tiled feature transform (layers 2,3; F_OUT=128) ----
// Block = 256 threads → 32 nodes × 256 output cols (h[0:128] ‖ rout[0:128]).
// Thread = 4 cols × 8 nodes (acc[8] ≈ 32 VGPR): 128 FMA per 64 B weight load
// while keeping occupancy ≥4 waves/SIMD (R5's 64-node tile collapsed occupancy
// to 18% → latency-bound at VALUBusy 49%).

template<int F_IN>
__global__ __launch_bounds__(256, 4) void tiled_feat_kernel(
    const float* __restrict__ xin, const float* __restrict__ W,
    const float* __restrict__ pw, const float* __restrict__ pb,
    const float* __restrict__ a_src, const float* __restrict__ a_dst,
    __half* __restrict__ h16, float* __restrict__ esrc, float* __restrict__ edst,
    float* __restrict__ rout)
{
    constexpr int F_OUT = 128;
    constexpr int TILE_M = 32;
    constexpr int K4 = F_IN / 4;
    __shared__ float4 xs4[TILE_M * K4];

    const int tid = threadIdx.x;
    const int cg  = tid & 63;           // col group: 4 cols starting at cg*4
    const int g   = tid >> 6;           // node group: 8 nodes starting at g*8
    const int base = blockIdx.x * TILE_M;

    constexpr int NV = TILE_M * K4;
    const float4* xg4 = (const float4*)xin;
    const int maxv = NN * K4 - 1;
#pragma unroll
    for (int i = tid; i < NV; i += 256) {
        int gi = base * K4 + i;
        xs4[i] = xg4[gi <= maxv ? gi : maxv];
    }
    __syncthreads();

    const int col4 = cg * 4;
    const bool isW = (col4 < F_OUT);
    const float* wbase = isW ? W : pw;
    const int f = isW ? col4 : (col4 - F_OUT);

    float4 acc[8];
#pragma unroll
    for (int i = 0; i < 8; ++i) acc[i] = make_float4(0.f, 0.f, 0.f, 0.f);

    for (int k0 = 0; k0 < F_IN; k0 += 4) {
        float4 w0 = *(const float4*)(wbase + (size_t)(k0 + 0) * F_OUT + f);
        float4 w1 = *(const float4*)(wbase + (size_t)(k0 + 1) * F_OUT + f);
        float4 w2 = *(const float4*)(wbase + (size_t)(k0 + 2) * F_OUT + f);
        float4 w3 = *(const float4*)(wbase + (size_t)(k0 + 3) * F_OUT + f);
#pragma unroll
        for (int i = 0; i < 8; ++i) {
            float4 xv = xs4[(g * 8 + i) * K4 + (k0 >> 2)];
            acc[i].x = fmaf(xv.x, w0.x, acc[i].x);
            acc[i].y = fmaf(xv.x, w0.y, acc[i].y);
            acc[i].z = fmaf(xv.x, w0.z, acc[i].z);
            acc[i].w = fmaf(xv.x, w0.w, acc[i].w);
            acc[i].x = fmaf(xv.y, w1.x, acc[i].x);
            acc[i].y = fmaf(xv.y, w1.y, acc[i].y);
            acc[i].z = fmaf(xv.y, w1.z, acc[i].z);
            acc[i].w = fmaf(xv.y, w1.w, acc[i].w);
            acc[i].x = fmaf(xv.z, w2.x, acc[i].x);
            acc[i].y = fmaf(xv.z, w2.y, acc[i].y);
            acc[i].z = fmaf(xv.z, w2.z, acc[i].z);
            acc[i].w = fmaf(xv.z, w2.w, acc[i].w);
            acc[i].x = fmaf(xv.w, w3.x, acc[i].x);
            acc[i].y = fmaf(xv.w, w3.y, acc[i].y);
            acc[i].z = fmaf(xv.w, w3.z, acc[i].z);
            acc[i].w = fmaf(xv.w, w3.w, acc[i].w);
        }
    }

    if (isW) {
        float4 av = *(const float4*)(a_src + f);
        float4 dv = *(const float4*)(a_dst + f);
        int head = cg >> 4;   // cols 0..63 = head0, 64..127 = head1
#pragma unroll
        for (int i = 0; i < 8; ++i) {
            int node = base + g * 8 + i;
            if (node < NN) {
                __half2* hp = (__half2*)(h16 + (size_t)node * F_OUT + f);
                hp[0] = __floats2half2_rn(acc[i].x, acc[i].y);
                hp[1] = __floats2half2_rn(acc[i].z, acc[i].w);
            }
            float es = acc[i].x * av.x + acc[i].y * av.y + acc[i].z * av.z + acc[i].w * av.w;
            float ed = acc[i].x * dv.x + acc[i].y * dv.y + acc[i].z * dv.z + acc[i].w * dv.w;
#pragma unroll
            for (int off = 8; off > 0; off >>= 1) {
                es += __shfl_xor(es, off, 16);
                ed += __shfl_xor(ed, off, 16);
            }
            if ((cg & 15) == 0 && node < NN) {
                esrc[node * 2 + head] = es;
                edst[node * 2 + head] = ed;
            }
        }
    } else {
        float4 bv = *(const float4*)(pb + f);
#pragma unroll
        for (int i = 0; i < 8; ++i) {
            int node = base + g * 8 + i;
            if (node < NN) {
                float4 r = acc[i];
                r.x += bv.x; r.y += bv.y; r.z += bv.z; r.w += bv.w;
                *(float4*)(rout + (size_t)node * F_OUT + f) = r;
            }
        }
    }
}

// ---------------- fused softmax-aggregate, F=128 ------------------------------
// One wave per dst node. Scalarized uniform stream (n, jb/je, csr idx, esrc)
// via readfirstlane → s_loads; vector pipe carries only the 8 h-row gathers.
// Masked unroll-8 (clamped idx, w=0) — no serial remainder loop.

__global__ __launch_bounds__(256) void aggregate128_kernel(
    const __half2* __restrict__ h2, const float2* __restrict__ esrc,
    const float2* __restrict__ edst,
    const int* __restrict__ row_ptr, const int* __restrict__ csr_src,
    const float* __restrict__ bias, const float* __restrict__ bng,
    const float* __restrict__ bnb, const float* __restrict__ bnm,
    const float* __restrict__ bnv, float* __restrict__ out, int nN)
{
    int lane = threadIdx.x & 63;
    int n = __builtin_amdgcn_readfirstlane(blockIdx.x * 4 + (threadIdx.x >> 6));
    if (n >= nN) return;
    float2 edv = edst[n];
    bool hi = lane >= 32;
    float ed = hi ? edv.y : edv.x;
    int jb = __builtin_amdgcn_readfirstlane(row_ptr[n]);
    int je = __builtin_amdgcn_readfirstlane(row_ptr[n + 1]);
    float s = 0.f, ax = 0.f, ay = 0.f;
    for (int j = jb; j < je; j += 8) {
        int idx[8];
#pragma unroll
        for (int u = 0; u < 8; ++u) {
            int jc = (j + u < je) ? (j + u) : (je - 1);
            idx[u] = __builtin_amdgcn_readfirstlane(csr_src[jc]);
        }
        float2 q[8];
        __half2 v[8];
#pragma unroll
        for (int u = 0; u < 8; ++u) {
            q[u] = esrc[idx[u]];
            v[u] = h2[(size_t)idx[u] * 64 + lane];
        }
#pragma unroll
        for (int u = 0; u < 8; ++u) {
            float a = (hi ? q[u].y : q[u].x) + ed;
            a = (a > 0.f) ? a : 0.2f * a;
            float wgt = (j + u < je) ? __expf(a) : 0.f;
            float2 f = __half22float2(v[u]);
            ax = fmaf(wgt, f.x, ax);
            ay = fmaf(wgt, f.y, ay);
            s += wgt;
        }
    }
    float inv = 1.f / (s + 1e-16f);
    int f0i = 2 * lane, f1i = 2 * lane + 1;
    float g0 = ax * inv, g1 = ay * inv;
    float o0 = bng[f0i] * (g0 + bias[f0i] - bnm[f0i]) * rsqrtf(bnv[f0i] + BNEPS) + bnb[f0i];
    float o1 = bng[f1i] * (g1 + bias[f1i] - bnm[f1i]) * rsqrtf(bnv[f1i] + BNEPS) + bnb[f1i];
    float2* op = (float2*)(out + (size_t)n * 128) + lane;
    float2 prev = *op;
    prev.x += fmaxf(o0, 0.f);
    prev.y += fmaxf(o1, 0.f);
    *op = prev;
}

// ---------------- fused softmax-aggregate, F=64 -------------------------------

__global__ __launch_bounds__(256) void aggregate64_kernel(
    const __half* __restrict__ h16, const float2* __restrict__ esrc,
    const float2* __restrict__ edst,
    const int* __restrict__ row_ptr, const int* __restrict__ csr_src,
    const float* __restrict__ bias, const float* __restrict__ bng,
    const float* __restrict__ bnb, const float* __restrict__ bnm,
    const float* __restrict__ bnv, float* __restrict__ out, int nN)
{
    int lane = threadIdx.x & 63;
    int n = __builtin_amdgcn_readfirstlane(blockIdx.x * 4 + (threadIdx.x >> 6));
    if (n >= nN) return;
    float2 edv = edst[n];
    bool hi = lane >= 32;
    float ed = hi ? edv.y : edv.x;
    int jb = __builtin_amdgcn_readfirstlane(row_ptr[n]);
    int je = __builtin_amdgcn_readfirstlane(row_ptr[n + 1]);
    float s = 0.f, acc = 0.f;
    for (int j = jb; j < je; j += 8) {
        int idx[8];
#pragma unroll
        for (int u = 0; u < 8; ++u) {
            int jc = (j + u < je) ? (j + u) : (je - 1);
            idx[u] = __builtin_amdgcn_readfirstlane(csr_src[jc]);
        }
        float2 q[8];
        float v[8];
#pragma unroll
        for (int u = 0; u < 8; ++u) {
            q[u] = esrc[idx[u]];
            v[u] = __half2float(h16[(size_t)idx[u] * 64 + lane]);
        }
#pragma unroll
        for (int u = 0; u < 8; ++u) {
            float a = (hi ? q[u].y : q[u].x) + ed;
            a = (a > 0.f) ? a : 0.2f * a;
            float wgt = (j + u < je) ? __expf(a) : 0.f;
            acc = fmaf(wgt, v[u], acc);
            s += wgt;
        }
    }
    int f = lane;
    float g = acc / (s + 1e-16f);
    float v = bng[f] * (g + bias[f] - bnm[f]) * rsqrtf(bnv[f] + BNEPS) + bnb[f];
    out[(size_t)n * 64 + f] = fmaxf(v, 0.f) + out[(size_t)n * 64 + f];
}

// ---------------- pooling (segment mean over sorted batch) ----------------

__global__ __launch_bounds__(128) void pool_kernel(const float* __restrict__ hfin,
                                                   const int* __restrict__ batch,
                                                   float* __restrict__ pooled) {
    int g = blockIdx.x;
    int f = threadIdx.x;
    int lo = 0, hi = NN;
    while (lo < hi) { int mid = (lo + hi) >> 1; if (batch[mid] < g) lo = mid + 1; else hi = mid; }
    int start = lo;
    hi = NN;
    while (lo < hi) { int mid = (lo + hi) >> 1; if (batch[mid] < g + 1) lo = mid + 1; else hi = mid; }
    int end = lo;
    float acc = 0.f;
    for (int i = start; i < end; ++i) acc += hfin[(size_t)i * 128 + f];
    float cnt = (float)(end - start);
    pooled[g * 128 + f] = acc / fmaxf(cnt, 1.0f);
}

// ---------------- MLP head ----------------

__global__ __launch_bounds__(128) void head_kernel(
    const float* __restrict__ pooled, const float* __restrict__ fw, const float* __restrict__ fb,
    const float* __restrict__ g4, const float* __restrict__ be4,
    const float* __restrict__ m4, const float* __restrict__ v4,
    const float* __restrict__ l1w, const float* __restrict__ l1b,
    const float* __restrict__ l2w, const float* __restrict__ l2b,
    float* __restrict__ out)
{
    __shared__ float p[128];
    __shared__ float z1[32];
    __shared__ float z2[32];
    int g = blockIdx.x, t = threadIdx.x;
    p[t] = pooled[g * 128 + t];
    __syncthreads();
    if (t < 32) {
        float acc = fb[t];
        for (int k = 0; k < 128; ++k) acc += p[k] * fw[k * 32 + t];
        float val = g4[t] * (acc - m4[t]) * rsqrtf(v4[t] + BNEPS) + be4[t];
        z1[t] = fmaxf(val, 0.f);
    }
    __syncthreads();
    if (t < 32) {
        float acc = l1b[t];
        for (int k = 0; k < 32; ++k) acc += z1[k] * l1w[k * 32 + t];
        z2[t] = fmaxf(acc, 0.f);
    }
    __syncthreads();
    if (t < 10) {
        float acc = l2b[t];
        for (int k = 0; k < 32; ++k) acc += z2[k] * l2w[k * 10 + t];
        out[g * 10 + t] = acc;
    }
}

// ---------------- launch ----------------

extern "C" void kernel_launch(void* const* d_in, const int* in_sizes, int n_in,
                              void* d_out, int out_size, void* d_ws, size_t ws_size,
                              hipStream_t stream) {
    const float* x     = (const float*)d_in[0];
    const int*   ei    = (const int*)d_in[1];
    const int*   batch = (const int*)d_in[2];
    const float* w1  = (const float*)d_in[3];
    const float* as1 = (const float*)d_in[4];
    const float* ad1 = (const float*)d_in[5];
    const float* b1  = (const float*)d_in[6];
    const float* g1  = (const float*)d_in[7];
    const float* be1 = (const float*)d_in[8];
    const float* m1  = (const float*)d_in[9];
    const float* v1  = (const float*)d_in[10];
    const float* p1w = (const float*)d_in[11];
    const float* p1b = (const float*)d_in[12];
    const float* w2  = (const float*)d_in[13];
    const float* as2 = (const float*)d_in[14];
    const float* ad2 = (const float*)d_in[15];
    const float* b2  = (const float*)d_in[16];
    const float* g2  = (const float*)d_in[17];
    const float* be2 = (const float*)d_in[18];
    const float* m2  = (const float*)d_in[19];
    const float* v2  = (const float*)d_in[20];
    const float* p2w = (const float*)d_in[21];
    const float* p2b = (const float*)d_in[22];
    const float* w3  = (const float*)d_in[23];
    const float* as3 = (const float*)d_in[24];
    const float* ad3 = (const float*)d_in[25];
    const float* b3  = (const float*)d_in[26];
    const float* g3  = (const float*)d_in[27];
    const float* be3 = (const float*)d_in[28];
    const float* m3  = (const float*)d_in[29];
    const float* v3  = (const float*)d_in[30];
    const float* p3w = (const float*)d_in[31];
    const float* p3b = (const float*)d_in[32];
    const float* fw  = (const float*)d_in[33];
    const float* fb  = (const float*)d_in[34];
    const float* g4  = (const float*)d_in[35];
    const float* be4 = (const float*)d_in[36];
    const float* m4  = (const float*)d_in[37];
    const float* v4  = (const float*)d_in[38];
    const float* l1w = (const float*)d_in[39];
    const float* l1b = (const float*)d_in[40];
    const float* l2w = (const float*)d_in[41];
    const float* l2b = (const float*)d_in[42];

    char* ws = (char*)d_ws;
    size_t off = 0;
    auto alloc = [&](size_t bytes) -> char* {
        char* p = ws + off;
        off += (bytes + 255) & ~(size_t)255;
        return p;
    };
    int*    bucket_cnt  = (int*)alloc((NBK) * sizeof(int));
    int*    bucket_base = (int*)alloc((NBK + 1) * sizeof(int));
    int*    gcursor     = (int*)alloc((NBK) * sizeof(int));
    int*    part        = (int*)alloc((size_t)ETOT * sizeof(int));
    int*    row_ptr     = (int*)alloc((NN + 1) * sizeof(int));
    int*    csr_src     = (int*)alloc((size_t)ETOT * sizeof(int));
    __half* h16         = (__half*)alloc((size_t)NN * 128 * sizeof(__half));
    float*  bufB        = (float*)alloc((size_t)NN * 128 * sizeof(float));
    float*  bufC        = (float*)alloc((size_t)NN * 128 * sizeof(float));
    float*  esrc        = (float*)alloc((size_t)NN * 2 * sizeof(float));
    float*  edst        = (float*)alloc((size_t)NN * 2 * sizeof(float));
    float*  pooled      = (float*)alloc((size_t)GG * 128 * sizeof(float));

    // ---- CSR build (bucketed partition) ----
    hipMemsetAsync(bucket_cnt, 0, NBK * sizeof(int), stream);
    bucket_count_kernel<<<(ETOT + 8191) / 8192, 256, 0, stream>>>(ei, bucket_cnt);
    bucket_scan_kernel<<<1, 512, 0, stream>>>(bucket_cnt, bucket_base, gcursor);
    partition_kernel<<<(ETOT + 4095) / 4096, 256, 0, stream>>>(ei, gcursor, part);
    csr_build_kernel<<<NBK, 256, 0, stream>>>(part, bucket_base, row_ptr, csr_src);

    // ---- layer 1: x[N,5] -> bufB[N,64] ----
    feat1_kernel<<<(NN + 3) / 4, 256, 0, stream>>>(
        x, w1, p1w, p1b, as1, ad1, h16, esrc, edst, bufB, NN);
    aggregate64_kernel<<<(NN + 3) / 4, 256, 0, stream>>>(
        h16, (const float2*)esrc, (const float2*)edst, row_ptr, csr_src,
        b1, g1, be1, m1, v1, bufB, NN);

    // ---- layer 2: bufB[N,64] -> bufC[N,128] ----
    tiled_feat_kernel<64><<<(NN + 31) / 32, 256, 0, stream>>>(
        bufB, w2, p2w, p2b, as2, ad2, h16, esrc, edst, bufC);
    aggregate128_kernel<<<(NN + 3) / 4, 256, 0, stream>>>(
        (const __half2*)h16, (const float2*)esrc, (const float2*)edst, row_ptr, csr_src,
        b2, g2, be2, m2, v2, bufC, NN);

    // ---- layer 3: bufC[N,128] -> bufB[N,128] ----
    tiled_feat_kernel<128><<<(NN + 31) / 32, 256, 0, stream>>>(
        bufC, w3, p3w, p3b, as3, ad3, h16, esrc, edst, bufB);
    aggregate128_kernel<<<(NN + 3) / 4, 256, 0, stream>>>(
        (const __half2*)h16, (const float2*)esrc, (const float2*)edst, row_ptr, csr_src,
        b3, g3, be3, m3, v3, bufB, NN);

    // ---- pool + head ----
    pool_kernel<<<GG, 128, 0, stream>>>(bufB, batch, pooled);
    head_kernel<<<GG, 128, 0, stream>>>(pooled, fw, fb, g4, be4, m4, v4,
                                        l1w, l1b, l2w, l2b, (float*)d_out);
}

// Round 7
// 813.095 us; speedup vs baseline: 1.0049x; 1.0049x over previous
//
#include <hip/hip_runtime.h>
#include <hip/hip_bf16.h>
#include <hip/hip_fp16.h>

#define NN   100000
#define EE   1600000
#define ETOT (EE + NN)
#define GG   256
#define BNEPS 1e-5f
#define NBK  391          // buckets of 256 nodes: (NN+255)/256

typedef float floatx2 __attribute__((ext_vector_type(2)));

// ---------------- CSR build: bucketed partition (single-writer cache lines) --

__global__ __launch_bounds__(256) void bucket_count_kernel(
    const int* __restrict__ ei, int* __restrict__ bucket_cnt)
{
    __shared__ int cnt[NBK];
    for (int i = threadIdx.x; i < NBK; i += 256) cnt[i] = 0;
    __syncthreads();
    int base = blockIdx.x * 8192;
    for (int k = threadIdx.x; k < 8192; k += 256) {
        int e = base + k;
        if (e < ETOT) {
            int dst = (e < EE) ? ei[EE + e] : (e - EE);
            atomicAdd(&cnt[dst >> 8], 1);
        }
    }
    __syncthreads();
    for (int i = threadIdx.x; i < NBK; i += 256)
        if (cnt[i]) atomicAdd(&bucket_cnt[i], cnt[i]);
}

__global__ __launch_bounds__(512) void bucket_scan_kernel(
    const int* __restrict__ bucket_cnt, int* __restrict__ bucket_base,
    int* __restrict__ gcursor)
{
    __shared__ int s[512];
    int t = threadIdx.x;
    int v = (t < NBK) ? bucket_cnt[t] : 0;
    s[t] = v;
    __syncthreads();
    int x = v;
    for (int o = 1; o < 512; o <<= 1) {
        int y = (t >= o) ? s[t - o] : 0;
        __syncthreads();
        x += y;
        s[t] = x;
        __syncthreads();
    }
    if (t < NBK) { bucket_base[t] = x - v; gcursor[t] = x - v; }
    if (t == 0) bucket_base[NBK] = ETOT;
}

__global__ __launch_bounds__(256) void partition_kernel(
    const int* __restrict__ ei, int* __restrict__ gcursor, int* __restrict__ part)
{
    __shared__ int cnt[NBK];
    __shared__ int basel[NBK];
    for (int i = threadIdx.x; i < NBK; i += 256) cnt[i] = 0;
    __syncthreads();
    int base = blockIdx.x * 4096;
    for (int k = threadIdx.x; k < 4096; k += 256) {
        int e = base + k;
        if (e < ETOT) {
            int dst = (e < EE) ? ei[EE + e] : (e - EE);
            atomicAdd(&cnt[dst >> 8], 1);
        }
    }
    __syncthreads();
    for (int i = threadIdx.x; i < NBK; i += 256) {
        int c = cnt[i];
        basel[i] = c ? atomicAdd(&gcursor[i], c) : 0;
        cnt[i] = 0;   // reuse as intra-block cursor
    }
    __syncthreads();
    for (int k = threadIdx.x; k < 4096; k += 256) {
        int e = base + k;
        if (e < ETOT) {
            int src, dst;
            if (e < EE) { src = ei[e]; dst = ei[EE + e]; }
            else        { src = e - EE; dst = e - EE; }
            int b = dst >> 8;
            int slot = atomicAdd(&cnt[b], 1);
            part[basel[b] + slot] = src | ((dst & 255) << 17);
        }
    }
}

__global__ __launch_bounds__(256) void csr_build_kernel(
    const int* __restrict__ part, const int* __restrict__ bucket_base,
    int* __restrict__ row_ptr, int* __restrict__ csr_src)
{
    __shared__ int deg[256];
    __shared__ int sc[256];
    int b = blockIdx.x;
    int t = threadIdx.x;
    int beg = bucket_base[b], end = bucket_base[b + 1];
    deg[t] = 0;
    __syncthreads();
    for (int j = beg + t; j < end; j += 256)
        atomicAdd(&deg[(part[j] >> 17) & 255], 1);
    __syncthreads();
    int v = deg[t];
    sc[t] = v;
    __syncthreads();
    int x = v;
    for (int o = 1; o < 256; o <<= 1) {
        int y = (t >= o) ? sc[t - o] : 0;
        __syncthreads();
        x += y;
        sc[t] = x;
        __syncthreads();
    }
    int excl = x - v;
    int node = b * 256 + t;
    if (node < NN) row_ptr[node] = beg + excl;
    __syncthreads();
    deg[t] = beg + excl;   // per-node global cursor
    __syncthreads();
    for (int j = beg + t; j < end; j += 256) {
        int pv = part[j];
        int pos = atomicAdd(&deg[(pv >> 17) & 255], 1);
        csr_src[pos] = pv & 0x1FFFF;
    }
    if (b == 0 && t == 0) row_ptr[NN] = ETOT;
}

// ---------------- layer-1 feature transform (K=5); h stored fp8 e4m3 ---------

__global__ __launch_bounds__(256) void feat1_kernel(
    const float* __restrict__ xin, const float* __restrict__ W,
    const float* __restrict__ pw, const float* __restrict__ pb,
    const float* __restrict__ a_src, const float* __restrict__ a_dst,
    unsigned char* __restrict__ h8, float* __restrict__ esrc, float* __restrict__ edst,
    float* __restrict__ rout, int nN)
{
    constexpr int F_IN = 5, F_OUT = 64;
    int t = threadIdx.x;
    int n = blockIdx.x * 4 + t / F_OUT;
    int f = t % F_OUT;
    if (n >= nN) return;
    float acc = 0.f, racc = 0.f;
#pragma unroll
    for (int k = 0; k < F_IN; ++k) {
        float xv = xin[n * F_IN + k];
        acc  += xv * W[k * F_OUT + f];
        racc += xv * pw[k * F_OUT + f];
    }
    // pair lanes (f, f^1) and let even lane store 2 fp8 bytes
    float other = __shfl_xor(acc, 1, 64);
    if ((f & 1) == 0) {
        int p = __builtin_amdgcn_cvt_pk_fp8_f32(acc, other, 0, false);
        *(unsigned short*)(h8 + (size_t)n * F_OUT + f) = (unsigned short)(p & 0xFFFF);
    }
    rout[(size_t)n * F_OUT + f] = racc + pb[f];
    float es = acc * a_src[f];
    float ed = acc * a_dst[f];
#pragma unroll
    for (int off = 16; off > 0; off >>= 1) {
        es += __shfl_xor(es, off, 32);
        ed += __shfl_xor(ed, off, 32);
    }
    if ((t & 31) == 0) {
        int head = (f >> 5) & 1;
        esrc[n * 2 + head] = es;
        edst[n * 2 + head] = ed;
    }
}

// ---------------- register-tiled feature transform (layers 2,3; F_OUT=128) ----
// 32 nodes × 256 cols per block; h stored fp8 e4m3 (4 cols → one 32-bit store).

template<int F_IN>
__global__ __launch_bounds__(256, 4) void tiled_feat_kernel(
    const float* __restrict__ xin, const float* __restrict__ W,
    const float* __restrict__ pw, const float* __restrict__ pb,
    const float* __restrict__ a_src, const float* __restrict__ a_dst,
    unsigned char* __restrict__ h8, float* __restrict__ esrc, float* __restrict__ edst,
    float* __restrict__ rout)
{
    constexpr int F_OUT = 128;
    constexpr int TILE_M = 32;
    constexpr int K4 = F_IN / 4;
    __shared__ float4 xs4[TILE_M * K4];

    const int tid = threadIdx.x;
    const int cg  = tid & 63;           // col group: 4 cols starting at cg*4
    const int g   = tid >> 6;           // node group: 8 nodes starting at g*8
    const int base = blockIdx.x * TILE_M;

    constexpr int NV = TILE_M * K4;
    const float4* xg4 = (const float4*)xin;
    const int maxv = NN * K4 - 1;
#pragma unroll
    for (int i = tid; i < NV; i += 256) {
        int gi = base * K4 + i;
        xs4[i] = xg4[gi <= maxv ? gi : maxv];
    }
    __syncthreads();

    const int col4 = cg * 4;
    const bool isW = (col4 < F_OUT);
    const float* wbase = isW ? W : pw;
    const int f = isW ? col4 : (col4 - F_OUT);

    float4 acc[8];
#pragma unroll
    for (int i = 0; i < 8; ++i) acc[i] = make_float4(0.f, 0.f, 0.f, 0.f);

    for (int k0 = 0; k0 < F_IN; k0 += 4) {
        float4 w0 = *(const float4*)(wbase + (size_t)(k0 + 0) * F_OUT + f);
        float4 w1 = *(const float4*)(wbase + (size_t)(k0 + 1) * F_OUT + f);
        float4 w2 = *(const float4*)(wbase + (size_t)(k0 + 2) * F_OUT + f);
        float4 w3 = *(const float4*)(wbase + (size_t)(k0 + 3) * F_OUT + f);
#pragma unroll
        for (int i = 0; i < 8; ++i) {
            float4 xv = xs4[(g * 8 + i) * K4 + (k0 >> 2)];
            acc[i].x = fmaf(xv.x, w0.x, acc[i].x);
            acc[i].y = fmaf(xv.x, w0.y, acc[i].y);
            acc[i].z = fmaf(xv.x, w0.z, acc[i].z);
            acc[i].w = fmaf(xv.x, w0.w, acc[i].w);
            acc[i].x = fmaf(xv.y, w1.x, acc[i].x);
            acc[i].y = fmaf(xv.y, w1.y, acc[i].y);
            acc[i].z = fmaf(xv.y, w1.z, acc[i].z);
            acc[i].w = fmaf(xv.y, w1.w, acc[i].w);
            acc[i].x = fmaf(xv.z, w2.x, acc[i].x);
            acc[i].y = fmaf(xv.z, w2.y, acc[i].y);
            acc[i].z = fmaf(xv.z, w2.z, acc[i].z);
            acc[i].w = fmaf(xv.z, w2.w, acc[i].w);
            acc[i].x = fmaf(xv.w, w3.x, acc[i].x);
            acc[i].y = fmaf(xv.w, w3.y, acc[i].y);
            acc[i].z = fmaf(xv.w, w3.z, acc[i].z);
            acc[i].w = fmaf(xv.w, w3.w, acc[i].w);
        }
    }

    if (isW) {
        float4 av = *(const float4*)(a_src + f);
        float4 dv = *(const float4*)(a_dst + f);
        int head = cg >> 4;   // cols 0..63 = head0, 64..127 = head1
#pragma unroll
        for (int i = 0; i < 8; ++i) {
            int node = base + g * 8 + i;
            if (node < NN) {
                int p = __builtin_amdgcn_cvt_pk_fp8_f32(acc[i].x, acc[i].y, 0, false);
                p = __builtin_amdgcn_cvt_pk_fp8_f32(acc[i].z, acc[i].w, p, true);
                *(int*)(h8 + (size_t)node * F_OUT + f) = p;
            }
            float es = acc[i].x * av.x + acc[i].y * av.y + acc[i].z * av.z + acc[i].w * av.w;
            float ed = acc[i].x * dv.x + acc[i].y * dv.y + acc[i].z * dv.z + acc[i].w * dv.w;
#pragma unroll
            for (int off = 8; off > 0; off >>= 1) {
                es += __shfl_xor(es, off, 16);
                ed += __shfl_xor(ed, off, 16);
            }
            if ((cg & 15) == 0 && node < NN) {
                esrc[node * 2 + head] = es;
                edst[node * 2 + head] = ed;
            }
        }
    } else {
        float4 bv = *(const float4*)(pb + f);
#pragma unroll
        for (int i = 0; i < 8; ++i) {
            int node = base + g * 8 + i;
            if (node < NN) {
                float4 r = acc[i];
                r.x += bv.x; r.y += bv.y; r.z += bv.z; r.w += bv.w;
                *(float4*)(rout + (size_t)node * F_OUT + f) = r;
            }
        }
    }
}

// ---------------- fused softmax-aggregate, F=128 (fp8 h, masked unroll x8) ---
// One wave per dst node; lane covers features 2*lane, 2*lane+1 via one ushort
// gather (wave reads the full 128 B row contiguously).

__global__ __launch_bounds__(256) void aggregate128_kernel(
    const unsigned short* __restrict__ h8s, const float2* __restrict__ esrc,
    const float2* __restrict__ edst,
    const int* __restrict__ row_ptr, const int* __restrict__ csr_src,
    const float* __restrict__ bias, const float* __restrict__ bng,
    const float* __restrict__ bnb, const float* __restrict__ bnm,
    const float* __restrict__ bnv, float* __restrict__ out, int nN)
{
    int w = threadIdx.x >> 6;
    int lane = threadIdx.x & 63;
    int n = blockIdx.x * 4 + w;
    if (n >= nN) return;
    float2 edv = edst[n];
    bool hi = lane >= 32;
    float ed = hi ? edv.y : edv.x;
    int jb = row_ptr[n], je = row_ptr[n + 1];
    float s = 0.f, ax = 0.f, ay = 0.f;
    for (int j = jb; j < je; j += 8) {
        int idx[8];
#pragma unroll
        for (int u = 0; u < 8; ++u) {
            int jc = (j + u < je) ? (j + u) : (je - 1);
            idx[u] = csr_src[jc];
        }
        float2 q[8];
        unsigned short v[8];
#pragma unroll
        for (int u = 0; u < 8; ++u) {
            q[u] = esrc[idx[u]];
            v[u] = h8s[(size_t)idx[u] * 64 + lane];
        }
#pragma unroll
        for (int u = 0; u < 8; ++u) {
            float a = (hi ? q[u].y : q[u].x) + ed;
            a = (a > 0.f) ? a : 0.2f * a;
            float wgt = (j + u < je) ? __expf(a) : 0.f;
            floatx2 f = __builtin_amdgcn_cvt_pk_f32_fp8((int)v[u], false);
            ax = fmaf(wgt, f.x, ax);
            ay = fmaf(wgt, f.y, ay);
            s += wgt;
        }
    }
    float inv = 1.f / (s + 1e-16f);
    int f0i = 2 * lane, f1i = 2 * lane + 1;
    float g0 = ax * inv, g1 = ay * inv;
    float o0 = bng[f0i] * (g0 + bias[f0i] - bnm[f0i]) * rsqrtf(bnv[f0i] + BNEPS) + bnb[f0i];
    float o1 = bng[f1i] * (g1 + bias[f1i] - bnm[f1i]) * rsqrtf(bnv[f1i] + BNEPS) + bnb[f1i];
    float2* op = (float2*)(out + (size_t)n * 128) + lane;
    float2 prev = *op;
    prev.x += fmaxf(o0, 0.f);
    prev.y += fmaxf(o1, 0.f);
    *op = prev;
}

// ---------------- fused softmax-aggregate, F=64 (fp8 h, masked unroll x8) ----

__global__ __launch_bounds__(256) void aggregate64_kernel(
    const unsigned char* __restrict__ h8, const float2* __restrict__ esrc,
    const float2* __restrict__ edst,
    const int* __restrict__ row_ptr, const int* __restrict__ csr_src,
    const float* __restrict__ bias, const float* __restrict__ bng,
    const float* __restrict__ bnb, const float* __restrict__ bnm,
    const float* __restrict__ bnv, float* __restrict__ out, int nN)
{
    int w = threadIdx.x >> 6;
    int lane = threadIdx.x & 63;
    int n = blockIdx.x * 4 + w;
    if (n >= nN) return;
    float2 edv = edst[n];
    bool hi = lane >= 32;
    float ed = hi ? edv.y : edv.x;
    int jb = row_ptr[n], je = row_ptr[n + 1];
    float s = 0.f, acc = 0.f;
    for (int j = jb; j < je; j += 8) {
        int idx[8];
#pragma unroll
        for (int u = 0; u < 8; ++u) {
            int jc = (j + u < je) ? (j + u) : (je - 1);
            idx[u] = csr_src[jc];
        }
        float2 q[8];
        unsigned char v[8];
#pragma unroll
        for (int u = 0; u < 8; ++u) {
            q[u] = esrc[idx[u]];
            v[u] = h8[(size_t)idx[u] * 64 + lane];
        }
#pragma unroll
        for (int u = 0; u < 8; ++u) {
            float a = (hi ? q[u].y : q[u].x) + ed;
            a = (a > 0.f) ? a : 0.2f * a;
            float wgt = (j + u < je) ? __expf(a) : 0.f;
            float fv = __builtin_amdgcn_cvt_f32_fp8((int)v[u], 0);
            acc = fmaf(wgt, fv, acc);
            s += wgt;
        }
    }
    int f = lane;
    float g = acc / (s + 1e-16f);
    float vv = bng[f] * (g + bias[f] - bnm[f]) * rsqrtf(bnv[f] + BNEPS) + bnb[f];
    out[(size_t)n * 64 + f] = fmaxf(vv, 0.f) + out[(size_t)n * 64 + f];
}

// ---------------- pooling (segment mean over sorted batch) ----------------

__global__ __launch_bounds__(128) void pool_kernel(const float* __restrict__ hfin,
                                                   const int* __restrict__ batch,
                                                   float* __restrict__ pooled) {
    int g = blockIdx.x;
    int f = threadIdx.x;
    int lo = 0, hi = NN;
    while (lo < hi) { int mid = (lo + hi) >> 1; if (batch[mid] < g) lo = mid + 1; else hi = mid; }
    int start = lo;
    hi = NN;
    while (lo < hi) { int mid = (lo + hi) >> 1; if (batch[mid] < g + 1) lo = mid + 1; else hi = mid; }
    int end = lo;
    float acc = 0.f;
    for (int i = start; i < end; ++i) acc += hfin[(size_t)i * 128 + f];
    float cnt = (float)(end - start);
    pooled[g * 128 + f] = acc / fmaxf(cnt, 1.0f);
}

// ---------------- MLP head ----------------

__global__ __launch_bounds__(128) void head_kernel(
    const float* __restrict__ pooled, const float* __restrict__ fw, const float* __restrict__ fb,
    const float* __restrict__ g4, const float* __restrict__ be4,
    const float* __restrict__ m4, const float* __restrict__ v4,
    const float* __restrict__ l1w, const float* __restrict__ l1b,
    const float* __restrict__ l2w, const float* __restrict__ l2b,
    float* __restrict__ out)
{
    __shared__ float p[128];
    __shared__ float z1[32];
    __shared__ float z2[32];
    int g = blockIdx.x, t = threadIdx.x;
    p[t] = pooled[g * 128 + t];
    __syncthreads();
    if (t < 32) {
        float acc = fb[t];
        for (int k = 0; k < 128; ++k) acc += p[k] * fw[k * 32 + t];
        float val = g4[t] * (acc - m4[t]) * rsqrtf(v4[t] + BNEPS) + be4[t];
        z1[t] = fmaxf(val, 0.f);
    }
    __syncthreads();
    if (t < 32) {
        float acc = l1b[t];
        for (int k = 0; k < 32; ++k) acc += z1[k] * l1w[k * 32 + t];
        z2[t] = fmaxf(acc, 0.f);
    }
    __syncthreads();
    if (t < 10) {
        float acc = l2b[t];
        for (int k = 0; k < 32; ++k) acc += z2[k] * l2w[k * 10 + t];
        out[g * 10 + t] = acc;
    }
}

// ---------------- launch ----------------

extern "C" void kernel_launch(void* const* d_in, const int* in_sizes, int n_in,
                              void* d_out, int out_size, void* d_ws, size_t ws_size,
                              hipStream_t stream) {
    const float* x     = (const float*)d_in[0];
    const int*   ei    = (const int*)d_in[1];
    const int*   batch = (const int*)d_in[2];
    const float* w1  = (const float*)d_in[3];
    const float* as1 = (const float*)d_in[4];
    const float* ad1 = (const float*)d_in[5];
    const float* b1  = (const float*)d_in[6];
    const float* g1  = (const float*)d_in[7];
    const float* be1 = (const float*)d_in[8];
    const float* m1  = (const float*)d_in[9];
    const float* v1  = (const float*)d_in[10];
    const float* p1w = (const float*)d_in[11];
    const float* p1b = (const float*)d_in[12];
    const float* w2  = (const float*)d_in[13];
    const float* as2 = (const float*)d_in[14];
    const float* ad2 = (const float*)d_in[15];
    const float* b2  = (const float*)d_in[16];
    const float* g2  = (const float*)d_in[17];
    const float* be2 = (const float*)d_in[18];
    const float* m2  = (const float*)d_in[19];
    const float* v2  = (const float*)d_in[20];
    const float* p2w = (const float*)d_in[21];
    const float* p2b = (const float*)d_in[22];
    const float* w3  = (const float*)d_in[23];
    const float* as3 = (const float*)d_in[24];
    const float* ad3 = (const float*)d_in[25];
    const float* b3  = (const float*)d_in[26];
    const float* g3  = (const float*)d_in[27];
    const float* be3 = (const float*)d_in[28];
    const float* m3  = (const float*)d_in[29];
    const float* v3  = (const float*)d_in[30];
    const float* p3w = (const float*)d_in[31];
    const float* p3b = (const float*)d_in[32];
    const float* fw  = (const float*)d_in[33];
    const float* fb  = (const float*)d_in[34];
    const float* g4  = (const float*)d_in[35];
    const float* be4 = (const float*)d_in[36];
    const float* m4  = (const float*)d_in[37];
    const float* v4  = (const float*)d_in[38];
    const float* l1w = (const float*)d_in[39];
    const float* l1b = (const float*)d_in[40];
    const float* l2w = (const float*)d_in[41];
    const float* l2b = (const float*)d_in[42];

    char* ws = (char*)d_ws;
    size_t off = 0;
    auto alloc = [&](size_t bytes) -> char* {
        char* p = ws + off;
        off += (bytes + 255) & ~(size_t)255;
        return p;
    };
    int*    bucket_cnt  = (int*)alloc((NBK) * sizeof(int));
    int*    bucket_base = (int*)alloc((NBK + 1) * sizeof(int));
    int*    gcursor     = (int*)alloc((NBK) * sizeof(int));
    int*    part        = (int*)alloc((size_t)ETOT * sizeof(int));
    int*    row_ptr     = (int*)alloc((NN + 1) * sizeof(int));
    int*    csr_src     = (int*)alloc((size_t)ETOT * sizeof(int));
    unsigned char* h8   = (unsigned char*)alloc((size_t)NN * 128);
    float*  bufB        = (float*)alloc((size_t)NN * 128 * sizeof(float));
    float*  bufC        = (float*)alloc((size_t)NN * 128 * sizeof(float));
    float*  esrc        = (float*)alloc((size_t)NN * 2 * sizeof(float));
    float*  edst        = (float*)alloc((size_t)NN * 2 * sizeof(float));
    float*  pooled      = (float*)alloc((size_t)GG * 128 * sizeof(float));

    // ---- CSR build (bucketed partition) ----
    hipMemsetAsync(bucket_cnt, 0, NBK * sizeof(int), stream);
    bucket_count_kernel<<<(ETOT + 8191) / 8192, 256, 0, stream>>>(ei, bucket_cnt);
    bucket_scan_kernel<<<1, 512, 0, stream>>>(bucket_cnt, bucket_base, gcursor);
    partition_kernel<<<(ETOT + 4095) / 4096, 256, 0, stream>>>(ei, gcursor, part);
    csr_build_kernel<<<NBK, 256, 0, stream>>>(part, bucket_base, row_ptr, csr_src);

    // ---- layer 1: x[N,5] -> bufB[N,64] ----
    feat1_kernel<<<(NN + 3) / 4, 256, 0, stream>>>(
        x, w1, p1w, p1b, as1, ad1, h8, esrc, edst, bufB, NN);
    aggregate64_kernel<<<(NN + 3) / 4, 256, 0, stream>>>(
        h8, (const float2*)esrc, (const float2*)edst, row_ptr, csr_src,
        b1, g1, be1, m1, v1, bufB, NN);

    // ---- layer 2: bufB[N,64] -> bufC[N,128] ----
    tiled_feat_kernel<64><<<(NN + 31) / 32, 256, 0, stream>>>(
        bufB, w2, p2w, p2b, as2, ad2, h8, esrc, edst, bufC);
    aggregate128_kernel<<<(NN + 3) / 4, 256, 0, stream>>>(
        (const unsigned short*)h8, (const float2*)esrc, (const float2*)edst, row_ptr, csr_src,
        b2, g2, be2, m2, v2, bufC, NN);

    // ---- layer 3: bufC[N,128] -> bufB[N,128] ----
    tiled_feat_kernel<128><<<(NN + 31) / 32, 256, 0, stream>>>(
        bufC, w3, p3w, p3b, as3, ad3, h8, esrc, edst, bufB);
    aggregate128_kernel<<<(NN + 3) / 4, 256, 0, stream>>>(
        (const unsigned short*)h8, (const float2*)esrc, (const float2*)edst, row_ptr, csr_src,
        b3, g3, be3, m3, v3, bufB, NN);

    // ---- pool + head ----
    pool_kernel<<<GG, 128, 0, stream>>>(bufB, batch, pooled);
    head_kernel<<<GG, 128, 0, stream>>>(pooled, fw, fb, g4, be4, m4, v4,
                                        l1w, l1b, l2w, l2b, (float*)d_out);
}